// Round 5
// baseline (1439.221 us; speedup 1.0000x reference)
//
#include <hip/hip_runtime.h>
#include <stdint.h>
#include <math.h>

typedef unsigned short u16;
typedef short  s16x8 __attribute__((ext_vector_type(8)));
typedef float  f32x4 __attribute__((ext_vector_type(4)));

#define DEVI __device__ __forceinline__

DEVI float b2f(u16 u){ union{unsigned int i; float f;} v; v.i = ((unsigned int)u)<<16; return v.f; }
DEVI u16 f2b(float f){
  union{float f; unsigned int i;} v; v.f = f;
  unsigned int r = v.i + 0x7FFFu + ((v.i >> 16) & 1u);   // RNE
  return (u16)(r >> 16);
}

// ---------------------------------------------------------------------------
// GEMM: C[M,N] = A[M,K] @ Bt[N,K]^T   (A,Bt bf16, fp32 accum, fp32 bias)
// MODE 0: store bf16 | MODE 1: bias + exact GELU, store bf16
// MODE 2: resid_f32[M,N] += acc + bias
// 128x128 tile, BK=32, 4 waves (2x2), 16x16x32 bf16 MFMA, explicit staging.
// ---------------------------------------------------------------------------
template<int MODE>
__launch_bounds__(256, 2)
__global__ void gemm_bt(const u16* __restrict__ A, const u16* __restrict__ Bt,
                        const float* __restrict__ bias, u16* __restrict__ outb,
                        float* __restrict__ resid, int M, int N, int K)
{
  __shared__ __align__(16) u16 lds_a[128*32];
  __shared__ __align__(16) u16 lds_b[128*32];
  const int tid = threadIdx.x;
  const int w = tid >> 6, l = tid & 63;
  const int q = l >> 4, r = l & 15;
  const int wm = w & 1, wn = w >> 1;
  const size_t m0 = (size_t)blockIdx.y * 128, n0 = (size_t)blockIdx.x * 128;

  const int srow = tid >> 2;            // staging row 0..63
  const int scol = (tid & 3) * 8;       // staging col (u16) 0/8/16/24
  const u16* pa0 = A  + (m0 + srow)      * (size_t)K + scol;
  const u16* pa1 = A  + (m0 + 64 + srow) * (size_t)K + scol;
  const u16* pb0 = Bt + (n0 + srow)      * (size_t)K + scol;
  const u16* pb1 = Bt + (n0 + 64 + srow) * (size_t)K + scol;

  f32x4 acc[4][4];
  f32x4 zero = {0.f, 0.f, 0.f, 0.f};
#pragma unroll
  for (int i = 0; i < 4; i++)
#pragma unroll
    for (int j = 0; j < 4; j++) acc[i][j] = zero;

  for (int k0 = 0; k0 < K; k0 += 32){
    s16x8 va0 = *(const s16x8*)(pa0 + k0);
    s16x8 va1 = *(const s16x8*)(pa1 + k0);
    s16x8 vb0 = *(const s16x8*)(pb0 + k0);
    s16x8 vb1 = *(const s16x8*)(pb1 + k0);
    __syncthreads();                       // prior fragment reads done
    *(s16x8*)&lds_a[srow*32 + scol]        = va0;
    *(s16x8*)&lds_a[(64 + srow)*32 + scol] = va1;
    *(s16x8*)&lds_b[srow*32 + scol]        = vb0;
    *(s16x8*)&lds_b[(64 + srow)*32 + scol] = vb1;
    __syncthreads();                       // tile visible

    s16x8 af[4], bfr[4];
#pragma unroll
    for (int mm = 0; mm < 4; mm++)
      af[mm] = *(const s16x8*)&lds_a[(wm*64 + mm*16 + r)*32 + q*8];
#pragma unroll
    for (int nn = 0; nn < 4; nn++)
      bfr[nn] = *(const s16x8*)&lds_b[(wn*64 + nn*16 + r)*32 + q*8];
#pragma unroll
    for (int mm = 0; mm < 4; mm++)
#pragma unroll
      for (int nn = 0; nn < 4; nn++)
        acc[mm][nn] = __builtin_amdgcn_mfma_f32_16x16x32_bf16(af[mm], bfr[nn], acc[mm][nn], 0, 0, 0);
  }

  // C/D layout: row = q*4+j, col = r  [m89/m91]
#pragma unroll
  for (int nn = 0; nn < 4; nn++){
    size_t col = n0 + wn*64 + nn*16 + r;
    float bv = (MODE == 0) ? 0.0f : bias[col];
#pragma unroll
    for (int mm = 0; mm < 4; mm++){
#pragma unroll
      for (int j = 0; j < 4; j++){
        size_t row = m0 + wm*64 + mm*16 + q*4 + j;
        float v = acc[mm][nn][j] + bv;
        if (MODE == 1) v = 0.5f * v * (1.0f + erff(v * 0.70710678118654752f));
        if (MODE == 2) resid[row * N + col] += v;
        else           outb[row * N + col] = f2b(v);
      }
    }
  }
}

// ---------------------------------------------------------------------------
// Zero-sink attention (flash-style). grid=(Nq/64, H, B), block=256 (4 waves).
// Wave owns 16 Q rows; KV tiles of 32. Sink == online-softmax init m=0, l=1.
// Q/K/V/O are bf16 internal buffers. Output at col h*64 of LD=768 rows.
// ---------------------------------------------------------------------------
__launch_bounds__(256, 2)
__global__ void attn_zero_kernel(const u16* __restrict__ Qp, const u16* __restrict__ Kp,
                                 const u16* __restrict__ Vp, u16* __restrict__ Op,
                                 int Nq, int Nkv, int LDq, int LDk, int LDv,
                                 float outw, int accumulate)
{
  __shared__ __align__(16) u16 lds_k[32*64];     // [kv=32][d=64], chunk slot = c ^ (kv&7)
  __shared__ __align__(16) u16 lds_v[64*32];     // [d=64][kv=32], chunk slot = c ^ (d&3)
  __shared__ __align__(16) u16 lds_p[4][16*32];  // per-wave P (C->A layout hop)

  const int tid = threadIdx.x;
  const int w = tid >> 6, l = tid & 63;
  const int q = l >> 4, r = l & 15;
  const int h = blockIdx.y, b = blockIdx.z;
  const int q0 = blockIdx.x * 64 + w * 16;

  s16x8 qf[2];
  {
    const u16* qrow = Qp + (size_t)(b*Nq + q0 + r) * LDq + h*64;
    qf[0] = *(const s16x8*)(qrow + q*8);
    qf[1] = *(const s16x8*)(qrow + 32 + q*8);
  }

  float m_[4], l_[4];
  f32x4 o[4];
  f32x4 zero = {0.f, 0.f, 0.f, 0.f};
#pragma unroll
  for (int j = 0; j < 4; j++){ m_[j] = 0.0f; l_[j] = 1.0f; }   // zero-sink init
#pragma unroll
  for (int nn = 0; nn < 4; nn++) o[nn] = zero;

  const u16* Kbase = Kp + (size_t)b * Nkv * LDk + h*64;
  const u16* Vbase = Vp + (size_t)b * Nkv * LDv + h*64;

  const int krow = tid >> 3, kc = tid & 7;   // staging: kv row 0..31, d-chunk 0..7

  for (int kv0 = 0; kv0 < Nkv; kv0 += 32){
    s16x8 kvv = *(const s16x8*)(Kbase + (size_t)(kv0 + krow) * LDk + kc*8);
    s16x8 vvv = *(const s16x8*)(Vbase + (size_t)(kv0 + krow) * LDv + kc*8);
    __syncthreads();
    *(s16x8*)&lds_k[(krow*8 + (kc ^ (krow & 7)))*8] = kvv;
#pragma unroll
    for (int e = 0; e < 8; e++){
      int d = kc*8 + e;
      lds_v[d*32 + (((krow >> 3) ^ (d & 3)) << 3) + (krow & 7)] = (u16)vvv[e];
    }
    __syncthreads();

    // S = (Q K^T) * 0.125 ; two 16-col kv sub-tiles
    f32x4 s[2];
#pragma unroll
    for (int kk = 0; kk < 2; kk++){
      int row = kk*16 + r;                   // kv index (B-fragment n)
      s16x8 kf0 = *(const s16x8*)&lds_k[(row*8 + ( q      ^ (row & 7)))*8];
      s16x8 kf1 = *(const s16x8*)&lds_k[(row*8 + ((4 + q) ^ (row & 7)))*8];
      f32x4 t = zero;
      t = __builtin_amdgcn_mfma_f32_16x16x32_bf16(qf[0], kf0, t, 0, 0, 0);
      t = __builtin_amdgcn_mfma_f32_16x16x32_bf16(qf[1], kf1, t, 0, 0, 0);
      s[kk] = t * 0.125f;
    }

    // online softmax per q-row (row q*4+j owned by the 16 lanes of quad q)
    float p0[4], p1[4], al[4];
#pragma unroll
    for (int j = 0; j < 4; j++){
      float mx = fmaxf(s[0][j], s[1][j]);
#pragma unroll
      for (int d = 1; d < 16; d <<= 1) mx = fmaxf(mx, __shfl_xor(mx, d));
      float mn = fmaxf(m_[j], mx);
      float a  = __expf(m_[j] - mn);
      p0[j] = __expf(s[0][j] - mn);
      p1[j] = __expf(s[1][j] - mn);
      float rs = p0[j] + p1[j];
#pragma unroll
      for (int d = 1; d < 16; d <<= 1) rs += __shfl_xor(rs, d);
      l_[j] = l_[j] * a + rs;
      m_[j] = mn; al[j] = a;
    }
#pragma unroll
    for (int nn = 0; nn < 4; nn++){
      f32x4 t = o[nn];
#pragma unroll
      for (int j = 0; j < 4; j++) t[j] *= al[j];
      o[nn] = t;
    }

    // P: C-layout -> LDS -> A-layout (wave-private)
    u16* P = &lds_p[w][0];
#pragma unroll
    for (int j = 0; j < 4; j++){
      P[(q*4 + j)*32 + r]      = f2b(p0[j]);
      P[(q*4 + j)*32 + 16 + r] = f2b(p1[j]);
    }
    s16x8 pf = *(const s16x8*)&P[r*32 + q*8];
#pragma unroll
    for (int nn = 0; nn < 4; nn++){
      int row = nn*16 + r;                   // d index (B-fragment n)
      s16x8 vf = *(const s16x8*)&lds_v[row*32 + ((q ^ (row & 3)) << 3)];
      o[nn] = __builtin_amdgcn_mfma_f32_16x16x32_bf16(pf, vf, o[nn], 0, 0, 0);
    }
  }

#pragma unroll
  for (int j = 0; j < 4; j++){
    float inv = outw / l_[j];
    size_t rowoff = (size_t)(b*Nq + q0 + q*4 + j) * 768 + h*64;
#pragma unroll
    for (int nn = 0; nn < 4; nn++){
      float v = o[nn][j] * inv;
      size_t idx = rowoff + nn*16 + r;
      if (accumulate) v += b2f(Op[idx]);
      Op[idx] = f2b(v);
    }
  }
}

// ---------------------------------------------------------------------------
// LayerNorm over D=768 fp32 rows -> bf16 out. One block (256) per row.
// gains/biases fp32.
// ---------------------------------------------------------------------------
__launch_bounds__(256)
__global__ void ln_kernel(const float* __restrict__ x, const float* __restrict__ g,
                          const float* __restrict__ bta, u16* __restrict__ out)
{
  __shared__ float red[8];
  const size_t row = blockIdx.x;
  const float* xr = x + row * 768;
  int t = threadIdx.x;
  float v0 = xr[t], v1 = xr[t + 256], v2 = xr[t + 512];
  float s  = v0 + v1 + v2;
  float s2 = v0*v0 + v1*v1 + v2*v2;
#pragma unroll
  for (int d = 1; d < 64; d <<= 1){ s += __shfl_xor(s, d); s2 += __shfl_xor(s2, d); }
  int w = t >> 6;
  if ((t & 63) == 0){ red[w] = s; red[4 + w] = s2; }
  __syncthreads();
  s  = red[0] + red[1] + red[2] + red[3];
  s2 = red[4] + red[5] + red[6] + red[7];
  float mean = s * (1.0f / 768.0f);
  float var  = s2 * (1.0f / 768.0f) - mean * mean;
  float rstd = rsqrtf(var + 1e-5f);
  u16* orow = out + row * 768;
  orow[t]       = f2b((v0 - mean) * rstd * g[t]       + bta[t]);
  orow[t + 256] = f2b((v1 - mean) * rstd * g[t + 256] + bta[t + 256]);
  orow[t + 512] = f2b((v2 - mean) * rstd * g[t + 512] + bta[t + 512]);
}

// fp32 -> bf16 transpose (R x C -> C x R), dims multiples of 64. block (64,4).
__global__ void transpose_kernel(const float* __restrict__ in, u16* __restrict__ out, int R, int C)
{
  __shared__ u16 tile[64][65];
  int c0 = blockIdx.x * 64, r0 = blockIdx.y * 64;
  for (int i = threadIdx.y; i < 64; i += 4)
    tile[i][threadIdx.x] = f2b(in[(size_t)(r0 + i) * C + c0 + threadIdx.x]);
  __syncthreads();
  for (int i = threadIdx.y; i < 64; i += 4)
    out[(size_t)(c0 + i) * R + r0 + threadIdx.x] = tile[threadIdx.x][i];
}

// fp32 -> fp32 vectorized copy (n multiple of 4). Replaces hipMemcpyAsync.
__global__ void copy_f32(const float* __restrict__ in, float* __restrict__ out, long n4){
  long i = (long)blockIdx.x * blockDim.x + threadIdx.x;
  long stride = (long)gridDim.x * blockDim.x;
  const f32x4* in4 = (const f32x4*)in;
  f32x4* out4 = (f32x4*)out;
  for (; i < n4; i += stride) out4[i] = in4[i];
}

// ---------------------------------------------------------------------------
extern "C" void kernel_launch(void* const* d_in, const int* in_sizes, int n_in,
                              void* d_out, int out_size, void* d_ws, size_t ws_size,
                              hipStream_t stream)
{
  const int B = 4, NI = 1024, NC = 256, D = 768, FF = 3072, H = 12, L = 2;
  const int RI = B * NI;   // 4096 img rows
  const int RC = B * NC;   // 1024 clinic rows

  const float* img    = (const float*)d_in[0];
  const float* clinic = (const float*)d_in[1];
  const float* ln1_g  = (const float*)d_in[2];
  const float* ln1_b  = (const float*)d_in[3];
  const float* w_qkv  = (const float*)d_in[4];
  const float* w_o    = (const float*)d_in[5];
  const float* b_o    = (const float*)d_in[6];
  const float* ln2_g  = (const float*)d_in[7];
  const float* ln2_b  = (const float*)d_in[8];
  const float* w_ff1  = (const float*)d_in[9];
  const float* b_ff1  = (const float*)d_in[10];
  const float* w_ff2  = (const float*)d_in[11];
  const float* b_ff2  = (const float*)d_in[12];
  const float* cn_i_g = (const float*)d_in[13];
  const float* cn_i_b = (const float*)d_in[14];
  const float* cn_c_g = (const float*)d_in[15];
  const float* cn_c_b = (const float*)d_in[16];
  const float* w_iq   = (const float*)d_in[17];
  const float* w_ik   = (const float*)d_in[18];
  const float* w_iv   = (const float*)d_in[19];
  const float* w_cq   = (const float*)d_in[20];
  const float* w_ck   = (const float*)d_in[21];
  const float* w_cv   = (const float*)d_in[22];
  const float* w_io   = (const float*)d_in[23];
  const float* b_io   = (const float*)d_in[24];
  const float* w_co   = (const float*)d_in[25];
  const float* b_co   = (const float*)d_in[26];
  const float* fn_i_g = (const float*)d_in[27];
  const float* fn_i_b = (const float*)d_in[28];
  const float* fn_c_g = (const float*)d_in[29];
  const float* fn_c_b = (const float*)d_in[30];
  const float* iff_w1 = (const float*)d_in[31];
  const float* iff_b1 = (const float*)d_in[32];
  const float* iff_w2 = (const float*)d_in[33];
  const float* iff_b2 = (const float*)d_in[34];
  const float* cff_w1 = (const float*)d_in[35];
  const float* cff_b1 = (const float*)d_in[36];
  const float* cff_w2 = (const float*)d_in[37];
  const float* cff_b2 = (const float*)d_in[38];

  // ---- workspace carve (~113 MB) ----
  char* ws = (char*)d_ws;
  size_t off = 0;
  auto alloc = [&](size_t elems, size_t esz) -> void* {
    void* p = ws + off;
    off += ((elems * esz) + 255) & ~(size_t)255;
    return p;
  };
  u16* wqkvT[2]; u16* woT[2]; u16* ff1T[2]; u16* ff2T[2];
  for (int i = 0; i < 2; i++) wqkvT[i] = (u16*)alloc((size_t)3*D*D, 2);
  for (int i = 0; i < 2; i++) woT[i]   = (u16*)alloc((size_t)D*D, 2);
  for (int i = 0; i < 2; i++) ff1T[i]  = (u16*)alloc((size_t)FF*D, 2);
  for (int i = 0; i < 2; i++) ff2T[i]  = (u16*)alloc((size_t)D*FF, 2);
  u16* wiqT = (u16*)alloc((size_t)D*D, 2); u16* wikT = (u16*)alloc((size_t)D*D, 2);
  u16* wivT = (u16*)alloc((size_t)D*D, 2); u16* wcqT = (u16*)alloc((size_t)D*D, 2);
  u16* wckT = (u16*)alloc((size_t)D*D, 2); u16* wcvT = (u16*)alloc((size_t)D*D, 2);
  u16* wioT = (u16*)alloc((size_t)D*D, 2); u16* wcoT = (u16*)alloc((size_t)D*D, 2);
  u16* iff1T = (u16*)alloc((size_t)FF*D, 2); u16* iff2T = (u16*)alloc((size_t)D*FF, 2);
  u16* cff1T = (u16*)alloc((size_t)FF*D, 2); u16* cff2T = (u16*)alloc((size_t)D*FF, 2);

  float* img_f = (float*)alloc((size_t)RI*D, 4);   // fp32 residual streams
  float* cli_f = (float*)alloc((size_t)RC*D, 4);
  u16* xn_i = (u16*)alloc((size_t)RI*D, 2);
  u16* xn_c = (u16*)alloc((size_t)RC*D, 2);
  // shared region: {qkvb | cqkv} (projections) or {h1} (FFN hidden)
  u16* region = (u16*)alloc((size_t)RI*FF, 2);   // RI*FF > RI*3D + RC*3D
  u16* qkvb = region;
  u16* cqkv = region + (size_t)RI*3*D;
  u16* h1   = region;
  u16* ao_i = (u16*)alloc((size_t)RI*D, 2);      // attention outputs (bf16)
  u16* ao_c = (u16*)alloc((size_t)RC*D, 2);
  (void)ws_size; (void)in_sizes; (void)n_in; (void)out_size;

  auto T = [&](const float* in_, u16* out_, int R, int C){
    transpose_kernel<<<dim3(C/64, R/64), dim3(64, 4), 0, stream>>>(in_, out_, R, C);
  };
  auto G0 = [&](const u16* A, const u16* Bt, u16* out_, int M, int N, int K){
    gemm_bt<0><<<dim3(N/128, M/128), 256, 0, stream>>>(A, Bt, nullptr, out_, nullptr, M, N, K);
  };
  auto G1 = [&](const u16* A, const u16* Bt, const float* bias, u16* out_, int M, int N, int K){
    gemm_bt<1><<<dim3(N/128, M/128), 256, 0, stream>>>(A, Bt, bias, out_, nullptr, M, N, K);
  };
  auto G2 = [&](const u16* A, const u16* Bt, const float* bias, float* resid, int M, int N, int K){
    gemm_bt<2><<<dim3(N/128, M/128), 256, 0, stream>>>(A, Bt, bias, nullptr, resid, M, N, K);
  };
  auto ATT = [&](const u16* Q, const u16* K_, const u16* V, u16* O,
                 int Nq, int Nkv, int LDq, int LDk, int LDv, float w_, int acc_){
    attn_zero_kernel<<<dim3(Nq/64, H, B), 256, 0, stream>>>(Q, K_, V, O, Nq, Nkv, LDq, LDk, LDv, w_, acc_);
  };
  auto CP = [&](const float* in_, float* out_, long n){
    copy_f32<<<1024, 256, 0, stream>>>(in_, out_, n / 4);
  };

  // ---- weight pre-transposes (K x N fp32 -> N x K bf16) ----
  for (int li = 0; li < L; li++){
    T(w_qkv + (size_t)li*D*3*D, wqkvT[li], D, 3*D);
    T(w_o   + (size_t)li*D*D,   woT[li],   D, D);
    T(w_ff1 + (size_t)li*D*FF,  ff1T[li],  D, FF);
    T(w_ff2 + (size_t)li*FF*D,  ff2T[li],  FF, D);
  }
  T(w_iq, wiqT, D, D); T(w_ik, wikT, D, D); T(w_iv, wivT, D, D);
  T(w_cq, wcqT, D, D); T(w_ck, wckT, D, D); T(w_cv, wcvT, D, D);
  T(w_io, wioT, D, D); T(w_co, wcoT, D, D);
  T(iff_w1, iff1T, D, FF); T(iff_w2, iff2T, FF, D);
  T(cff_w1, cff1T, D, FF); T(cff_w2, cff2T, FF, D);

  // ---- fp32 residual streams ----
  CP(img,    img_f, (long)RI*D);
  CP(clinic, cli_f, (long)RC*D);

  // ---- transformer stack ----
  for (int li = 0; li < L; li++){
    ln_kernel<<<RI, 256, 0, stream>>>(img_f, ln1_g + li*D, ln1_b + li*D, xn_i);
    G0(xn_i, wqkvT[li], qkvb, RI, 3*D, D);
    ATT(qkvb, qkvb + D, qkvb + 2*D, ao_i, NI, NI, 3*D, 3*D, 3*D, 1.0f, 0);
    G2(ao_i, woT[li], b_o + li*D, img_f, RI, D, D);
    ln_kernel<<<RI, 256, 0, stream>>>(img_f, ln2_g + li*D, ln2_b + li*D, xn_i);
    G1(xn_i, ff1T[li], b_ff1 + li*FF, h1, RI, FF, D);
    G2(h1, ff2T[li], b_ff2 + li*D, img_f, RI, D, FF);
  }

  // ---- cross block ----
  ln_kernel<<<RI, 256, 0, stream>>>(img_f, cn_i_g, cn_i_b, xn_i);
  ln_kernel<<<RC, 256, 0, stream>>>(cli_f, cn_c_g, cn_c_b, xn_c);
  u16* iq = qkvb;  u16* ik = qkvb + (size_t)RI*D;  u16* iv = qkvb + (size_t)2*RI*D;
  u16* cq = cqkv;  u16* ck = cqkv + (size_t)RC*D;  u16* cv = cqkv + (size_t)2*RC*D;
  G0(xn_i, wiqT, iq, RI, D, D);
  G0(xn_i, wikT, ik, RI, D, D);
  G0(xn_i, wivT, iv, RI, D, D);
  G0(xn_c, wcqT, cq, RC, D, D);
  G0(xn_c, wckT, ck, RC, D, D);
  G0(xn_c, wcvT, cv, RC, D, D);

  ATT(iq, ck, cv, ao_i, NI, NC, D, D, D, 0.5f, 0);
  ATT(iq, ik, iv, ao_i, NI, NI, D, D, D, 0.5f, 1);
  ATT(cq, ik, iv, ao_c, NC, NI, D, D, D, 0.5f, 0);
  ATT(cq, ck, cv, ao_c, NC, NC, D, D, D, 0.5f, 1);

  G2(ao_i, wioT, b_io, img_f, RI, D, D);
  G2(ao_c, wcoT, b_co, cli_f, RC, D, D);

  ln_kernel<<<RI, 256, 0, stream>>>(img_f, fn_i_g, fn_i_b, xn_i);
  G1(xn_i, iff1T, iff_b1, h1, RI, FF, D);
  G2(h1, iff2T, iff_b2, img_f, RI, D, FF);

  ln_kernel<<<RC, 256, 0, stream>>>(cli_f, fn_c_g, fn_c_b, xn_c);
  G1(xn_c, cff1T, cff_b1, h1, RC, FF, D);
  G2(h1, cff2T, cff_b2, cli_f, RC, D, FF);

  // ---- emit fp32 outputs (img then clinic, flat) ----
  CP(img_f, (float*)d_out,                (long)RI*D);
  CP(cli_f, (float*)d_out + (size_t)RI*D, (long)RC*D);
}

// Round 7
// 1383.815 us; speedup vs baseline: 1.0400x; 1.0400x over previous
//
#include <hip/hip_runtime.h>
#include <stdint.h>
#include <math.h>

typedef unsigned short u16;
typedef short  s16x8 __attribute__((ext_vector_type(8)));
typedef float  f32x4 __attribute__((ext_vector_type(4)));

#define DEVI __device__ __forceinline__

DEVI float b2f(u16 u){ union{unsigned int i; float f;} v; v.i = ((unsigned int)u)<<16; return v.f; }
DEVI u16 f2b(float f){
  union{float f; unsigned int i;} v; v.f = f;
  unsigned int r = v.i + 0x7FFFu + ((v.i >> 16) & 1u);   // RNE
  return (u16)(r >> 16);
}

// ---------------------------------------------------------------------------
// GEMM: C[M,N] = A[M,K] @ Bt[N,K]^T   (A,Bt bf16, fp32 accum, fp32 bias)
// MODE 0: store bf16 | MODE 1: bias + exact GELU, store bf16
// MODE 2: resid_f32[M,N] += acc + bias
// 128x128 tile, BK=32, 4 waves (2x2), 16x16x32 bf16 MFMA, explicit staging.
// (round-5 verified-good version; no global_load_lds)
// ---------------------------------------------------------------------------
template<int MODE>
__launch_bounds__(256, 2)
__global__ void gemm_bt(const u16* __restrict__ A, const u16* __restrict__ Bt,
                        const float* __restrict__ bias, u16* __restrict__ outb,
                        float* __restrict__ resid, int M, int N, int K)
{
  __shared__ __align__(16) u16 lds_a[128*32];
  __shared__ __align__(16) u16 lds_b[128*32];
  const int tid = threadIdx.x;
  const int w = tid >> 6, l = tid & 63;
  const int q = l >> 4, r = l & 15;
  const int wm = w & 1, wn = w >> 1;
  const size_t m0 = (size_t)blockIdx.y * 128, n0 = (size_t)blockIdx.x * 128;

  const int srow = tid >> 2;            // staging row 0..63
  const int scol = (tid & 3) * 8;       // staging col (u16) 0/8/16/24
  const u16* pa0 = A  + (m0 + srow)      * (size_t)K + scol;
  const u16* pa1 = A  + (m0 + 64 + srow) * (size_t)K + scol;
  const u16* pb0 = Bt + (n0 + srow)      * (size_t)K + scol;
  const u16* pb1 = Bt + (n0 + 64 + srow) * (size_t)K + scol;

  f32x4 acc[4][4];
  f32x4 zero = {0.f, 0.f, 0.f, 0.f};
#pragma unroll
  for (int i = 0; i < 4; i++)
#pragma unroll
    for (int j = 0; j < 4; j++) acc[i][j] = zero;

  for (int k0 = 0; k0 < K; k0 += 32){
    s16x8 va0 = *(const s16x8*)(pa0 + k0);
    s16x8 va1 = *(const s16x8*)(pa1 + k0);
    s16x8 vb0 = *(const s16x8*)(pb0 + k0);
    s16x8 vb1 = *(const s16x8*)(pb1 + k0);
    __syncthreads();                       // prior fragment reads done
    *(s16x8*)&lds_a[srow*32 + scol]        = va0;
    *(s16x8*)&lds_a[(64 + srow)*32 + scol] = va1;
    *(s16x8*)&lds_b[srow*32 + scol]        = vb0;
    *(s16x8*)&lds_b[(64 + srow)*32 + scol] = vb1;
    __syncthreads();                       // tile visible

    s16x8 af[4], bfr[4];
#pragma unroll
    for (int mm = 0; mm < 4; mm++)
      af[mm] = *(const s16x8*)&lds_a[(wm*64 + mm*16 + r)*32 + q*8];
#pragma unroll
    for (int nn = 0; nn < 4; nn++)
      bfr[nn] = *(const s16x8*)&lds_b[(wn*64 + nn*16 + r)*32 + q*8];
#pragma unroll
    for (int mm = 0; mm < 4; mm++)
#pragma unroll
      for (int nn = 0; nn < 4; nn++)
        acc[mm][nn] = __builtin_amdgcn_mfma_f32_16x16x32_bf16(af[mm], bfr[nn], acc[mm][nn], 0, 0, 0);
  }

  // C/D layout: row = q*4+j, col = r  [m89/m91]
#pragma unroll
  for (int nn = 0; nn < 4; nn++){
    size_t col = n0 + wn*64 + nn*16 + r;
    float bv = (MODE == 0) ? 0.0f : bias[col];
#pragma unroll
    for (int mm = 0; mm < 4; mm++){
#pragma unroll
      for (int j = 0; j < 4; j++){
        size_t row = m0 + wm*64 + mm*16 + q*4 + j;
        float v = acc[mm][nn][j] + bv;
        if (MODE == 1) v = 0.5f * v * (1.0f + erff(v * 0.70710678118654752f));
        if (MODE == 2) resid[row * N + col] += v;
        else           outb[row * N + col] = f2b(v);
      }
    }
  }
}

// ---------------------------------------------------------------------------
// Zero-sink attention (flash-style). grid=(Nq/64, H, B), block=256 (4 waves).
// V comes PRE-TRANSPOSED in global: vT[b][768][Nkv] (head h at rows h*64..).
// K tile [32][64] LDS with xor-chunk swizzle applied on the GLOBAL side; Vt
// tile [64][32] linear. Both staged with contiguous b128 writes (conflict-
// free). Sink == online-softmax init m=0, l=1. Output at col h*64, LD=768.
// ---------------------------------------------------------------------------
__launch_bounds__(256, 2)
__global__ void attn_zero_kernel(const u16* __restrict__ Qp, const u16* __restrict__ Kp,
                                 const u16* __restrict__ vT, u16* __restrict__ Op,
                                 int Nq, int Nkv, int LDq, int LDk,
                                 float outw, int accumulate)
{
  __shared__ __align__(16) u16 lds_k[32*64];     // [kv][d], slot-chunk s holds global chunk s^(kv&7)
  __shared__ __align__(16) u16 lds_v[64*32];     // [d][kv], linear
  __shared__ __align__(16) u16 lds_p[4][16*40];  // per-wave P, pitch 40 (4-way max on stores)

  const int tid = threadIdx.x;
  const int w = tid >> 6, l = tid & 63;
  const int q = l >> 4, r = l & 15;
  const int h = blockIdx.y, b = blockIdx.z;
  const int q0 = blockIdx.x * 64 + w * 16;

  s16x8 qf[2];
  {
    const u16* qrow = Qp + (size_t)(b*Nq + q0 + r) * LDq + h*64;
    qf[0] = *(const s16x8*)(qrow + q*8);
    qf[1] = *(const s16x8*)(qrow + 32 + q*8);
  }

  float m_[4], l_[4];
  f32x4 o[4];
  f32x4 zero = {0.f, 0.f, 0.f, 0.f};
#pragma unroll
  for (int j = 0; j < 4; j++){ m_[j] = 0.0f; l_[j] = 1.0f; }   // zero-sink init
#pragma unroll
  for (int nn = 0; nn < 4; nn++) o[nn] = zero;

  // staging: K chunk c=tid -> kvrow=c>>3, slot-cc=c&7, global-cc=(c&7)^(kvrow&7)
  const u16* Kbase = Kp + (size_t)b * Nkv * LDk + h*64;
  const u16* gk = Kbase + (size_t)(tid >> 3) * LDk + (((tid & 7) ^ ((tid >> 3) & 7)) << 3);
  // Vt chunk c=tid -> drow=c>>2, cc=c&3 (linear)
  const u16* Vbase = vT + ((size_t)b * 768 + h*64) * (size_t)Nkv;
  const u16* gv = Vbase + (size_t)(tid >> 2) * Nkv + ((tid & 3) << 3);

  for (int kv0 = 0; kv0 < Nkv; kv0 += 32){
    s16x8 kvv = *(const s16x8*)(gk + (size_t)kv0 * LDk);
    s16x8 vvv = *(const s16x8*)(gv + kv0);
    __syncthreads();
    *(s16x8*)&lds_k[tid * 8] = kvv;       // contiguous b128 stores: conflict-free
    *(s16x8*)&lds_v[tid * 8] = vvv;
    __syncthreads();

    // S = (Q K^T) * 0.125 ; kv columns kk*16+r
    f32x4 s[2];
#pragma unroll
    for (int kk = 0; kk < 2; kk++){
      int row = kk*16 + r;
      s16x8 kf0 = *(const s16x8*)&lds_k[row*64 + ((q       ^ (row & 7)) << 3)];
      s16x8 kf1 = *(const s16x8*)&lds_k[row*64 + (((4 + q) ^ (row & 7)) << 3)];
      f32x4 t = zero;
      t = __builtin_amdgcn_mfma_f32_16x16x32_bf16(qf[0], kf0, t, 0, 0, 0);
      t = __builtin_amdgcn_mfma_f32_16x16x32_bf16(qf[1], kf1, t, 0, 0, 0);
      s[kk] = t * 0.125f;
    }

    // online softmax per q-row (row q*4+j owned by the 16 lanes of quad q)
    float p0[4], p1[4], al[4];
#pragma unroll
    for (int j = 0; j < 4; j++){
      float mx = fmaxf(s[0][j], s[1][j]);
#pragma unroll
      for (int d = 1; d < 16; d <<= 1) mx = fmaxf(mx, __shfl_xor(mx, d));
      float mn = fmaxf(m_[j], mx);
      float a  = __expf(m_[j] - mn);
      p0[j] = __expf(s[0][j] - mn);
      p1[j] = __expf(s[1][j] - mn);
      float rs = p0[j] + p1[j];
#pragma unroll
      for (int d = 1; d < 16; d <<= 1) rs += __shfl_xor(rs, d);
      l_[j] = l_[j] * a + rs;
      m_[j] = mn; al[j] = a;
    }
#pragma unroll
    for (int nn = 0; nn < 4; nn++){
      f32x4 t = o[nn];
#pragma unroll
      for (int j = 0; j < 4; j++) t[j] *= al[j];
      o[nn] = t;
    }

    // P: C-layout -> LDS -> A-layout (wave-private; pitch 40, aligned b128 reads)
    u16* P = &lds_p[w][0];
#pragma unroll
    for (int j = 0; j < 4; j++){
      P[(q*4 + j)*40 + r]      = f2b(p0[j]);
      P[(q*4 + j)*40 + 16 + r] = f2b(p1[j]);
    }
    s16x8 pf = *(const s16x8*)&P[r*40 + q*8];
#pragma unroll
    for (int nn = 0; nn < 4; nn++){
      int row = nn*16 + r;                   // d index (B-fragment n)
      s16x8 vf = *(const s16x8*)&lds_v[row*32 + (q << 3)];
      o[nn] = __builtin_amdgcn_mfma_f32_16x16x32_bf16(pf, vf, o[nn], 0, 0, 0);
    }
  }

#pragma unroll
  for (int j = 0; j < 4; j++){
    float inv = outw / l_[j];
    size_t rowoff = (size_t)(b*Nq + q0 + q*4 + j) * 768 + h*64;
#pragma unroll
    for (int nn = 0; nn < 4; nn++){
      float v = o[nn][j] * inv;
      size_t idx = rowoff + nn*16 + r;
      if (accumulate) v += b2f(Op[idx]);
      Op[idx] = f2b(v);
    }
  }
}

// ---------------------------------------------------------------------------
// LayerNorm over D=768 fp32 rows -> bf16 out. One block (256) per row.
// ---------------------------------------------------------------------------
__launch_bounds__(256)
__global__ void ln_kernel(const float* __restrict__ x, const float* __restrict__ g,
                          const float* __restrict__ bta, u16* __restrict__ out)
{
  __shared__ float red[8];
  const size_t row = blockIdx.x;
  const float* xr = x + row * 768;
  int t = threadIdx.x;
  float v0 = xr[t], v1 = xr[t + 256], v2 = xr[t + 512];
  float s  = v0 + v1 + v2;
  float s2 = v0*v0 + v1*v1 + v2*v2;
#pragma unroll
  for (int d = 1; d < 64; d <<= 1){ s += __shfl_xor(s, d); s2 += __shfl_xor(s2, d); }
  int w = t >> 6;
  if ((t & 63) == 0){ red[w] = s; red[4 + w] = s2; }
  __syncthreads();
  s  = red[0] + red[1] + red[2] + red[3];
  s2 = red[4] + red[5] + red[6] + red[7];
  float mean = s * (1.0f / 768.0f);
  float var  = s2 * (1.0f / 768.0f) - mean * mean;
  float rstd = rsqrtf(var + 1e-5f);
  u16* orow = out + row * 768;
  orow[t]       = f2b((v0 - mean) * rstd * g[t]       + bta[t]);
  orow[t + 256] = f2b((v1 - mean) * rstd * g[t + 256] + bta[t + 256]);
  orow[t + 512] = f2b((v2 - mean) * rstd * g[t + 512] + bta[t + 512]);
}

// fp32 -> bf16 transpose (R x C -> C x R), dims multiples of 64. block (64,4).
__global__ void transpose_kernel(const float* __restrict__ in, u16* __restrict__ out, int R, int C)
{
  __shared__ u16 tile[64][65];
  int c0 = blockIdx.x * 64, r0 = blockIdx.y * 64;
  for (int i = threadIdx.y; i < 64; i += 4)
    tile[i][threadIdx.x] = f2b(in[(size_t)(r0 + i) * C + c0 + threadIdx.x]);
  __syncthreads();
  for (int i = threadIdx.y; i < 64; i += 4)
    out[(size_t)(c0 + i) * R + r0 + threadIdx.x] = tile[threadIdx.x][i];
}

// batched u16 transpose for V: in = per-batch [N][LD] slab at col offset coff,
// out = [b][768][N]. grid (768/64, N/64, B), block (64,4).
__global__ void transpose_v_kernel(const u16* __restrict__ in, u16* __restrict__ out,
                                   int N, int LD, int coff)
{
  __shared__ u16 tile[64][65];
  int bz = blockIdx.z;
  int c0 = blockIdx.x * 64, n0 = blockIdx.y * 64;
  const u16* ib = in + ((size_t)bz * N + n0) * LD + coff + c0;
  for (int i = threadIdx.y; i < 64; i += 4)
    tile[i][threadIdx.x] = ib[(size_t)i * LD + threadIdx.x];     // token n0+i, chan c0+tx
  __syncthreads();
  u16* ob = out + ((size_t)bz * 768 + c0) * N + n0;
  for (int i = threadIdx.y; i < 64; i += 4)
    ob[(size_t)i * N + threadIdx.x] = tile[threadIdx.x][i];      // chan c0+i, token n0+tx
}

// fp32 vectorized copy (n multiple of 4).
__global__ void copy_f32(const float* __restrict__ in, float* __restrict__ out, long n4){
  long i = (long)blockIdx.x * blockDim.x + threadIdx.x;
  long stride = (long)gridDim.x * blockDim.x;
  const f32x4* in4 = (const f32x4*)in;
  f32x4* out4 = (f32x4*)out;
  for (; i < n4; i += stride) out4[i] = in4[i];
}

// ---------------------------------------------------------------------------
extern "C" void kernel_launch(void* const* d_in, const int* in_sizes, int n_in,
                              void* d_out, int out_size, void* d_ws, size_t ws_size,
                              hipStream_t stream)
{
  const int B = 4, NI = 1024, NC = 256, D = 768, FF = 3072, H = 12, L = 2;
  const int RI = B * NI;   // 4096 img rows
  const int RC = B * NC;   // 1024 clinic rows

  const float* img    = (const float*)d_in[0];
  const float* clinic = (const float*)d_in[1];
  const float* ln1_g  = (const float*)d_in[2];
  const float* ln1_b  = (const float*)d_in[3];
  const float* w_qkv  = (const float*)d_in[4];
  const float* w_o    = (const float*)d_in[5];
  const float* b_o    = (const float*)d_in[6];
  const float* ln2_g  = (const float*)d_in[7];
  const float* ln2_b  = (const float*)d_in[8];
  const float* w_ff1  = (const float*)d_in[9];
  const float* b_ff1  = (const float*)d_in[10];
  const float* w_ff2  = (const float*)d_in[11];
  const float* b_ff2  = (const float*)d_in[12];
  const float* cn_i_g = (const float*)d_in[13];
  const float* cn_i_b = (const float*)d_in[14];
  const float* cn_c_g = (const float*)d_in[15];
  const float* cn_c_b = (const float*)d_in[16];
  const float* w_iq   = (const float*)d_in[17];
  const float* w_ik   = (const float*)d_in[18];
  const float* w_iv   = (const float*)d_in[19];
  const float* w_cq   = (const float*)d_in[20];
  const float* w_ck   = (const float*)d_in[21];
  const float* w_cv   = (const float*)d_in[22];
  const float* w_io   = (const float*)d_in[23];
  const float* b_io   = (const float*)d_in[24];
  const float* w_co   = (const float*)d_in[25];
  const float* b_co   = (const float*)d_in[26];
  const float* fn_i_g = (const float*)d_in[27];
  const float* fn_i_b = (const float*)d_in[28];
  const float* fn_c_g = (const float*)d_in[29];
  const float* fn_c_b = (const float*)d_in[30];
  const float* iff_w1 = (const float*)d_in[31];
  const float* iff_b1 = (const float*)d_in[32];
  const float* iff_w2 = (const float*)d_in[33];
  const float* iff_b2 = (const float*)d_in[34];
  const float* cff_w1 = (const float*)d_in[35];
  const float* cff_b1 = (const float*)d_in[36];
  const float* cff_w2 = (const float*)d_in[37];
  const float* cff_b2 = (const float*)d_in[38];

  // ---- workspace carve (~121 MB) ----
  char* ws = (char*)d_ws;
  size_t off = 0;
  auto alloc = [&](size_t elems, size_t esz) -> void* {
    void* p = ws + off;
    off += ((elems * esz) + 255) & ~(size_t)255;
    return p;
  };
  u16* wqkvT[2]; u16* woT[2]; u16* ff1T[2]; u16* ff2T[2];
  for (int i = 0; i < 2; i++) wqkvT[i] = (u16*)alloc((size_t)3*D*D, 2);
  for (int i = 0; i < 2; i++) woT[i]   = (u16*)alloc((size_t)D*D, 2);
  for (int i = 0; i < 2; i++) ff1T[i]  = (u16*)alloc((size_t)FF*D, 2);
  for (int i = 0; i < 2; i++) ff2T[i]  = (u16*)alloc((size_t)D*FF, 2);
  u16* wiqT = (u16*)alloc((size_t)D*D, 2); u16* wikT = (u16*)alloc((size_t)D*D, 2);
  u16* wivT = (u16*)alloc((size_t)D*D, 2); u16* wcqT = (u16*)alloc((size_t)D*D, 2);
  u16* wckT = (u16*)alloc((size_t)D*D, 2); u16* wcvT = (u16*)alloc((size_t)D*D, 2);
  u16* wioT = (u16*)alloc((size_t)D*D, 2); u16* wcoT = (u16*)alloc((size_t)D*D, 2);
  u16* iff1T = (u16*)alloc((size_t)FF*D, 2); u16* iff2T = (u16*)alloc((size_t)D*FF, 2);
  u16* cff1T = (u16*)alloc((size_t)FF*D, 2); u16* cff2T = (u16*)alloc((size_t)D*FF, 2);

  float* img_f = (float*)alloc((size_t)RI*D, 4);   // fp32 residual streams
  float* cli_f = (float*)alloc((size_t)RC*D, 4);
  u16* xn_i = (u16*)alloc((size_t)RI*D, 2);
  u16* xn_c = (u16*)alloc((size_t)RC*D, 2);
  // shared region: {qkvb | cqkv} (projections) or {h1} (FFN hidden)
  u16* region = (u16*)alloc((size_t)RI*FF, 2);   // RI*FF > RI*3D + RC*3D
  u16* qkvb = region;
  u16* cqkv = region + (size_t)RI*3*D;
  u16* h1   = region;
  u16* ao_i = (u16*)alloc((size_t)RI*D, 2);      // attention outputs (bf16)
  u16* ao_c = (u16*)alloc((size_t)RC*D, 2);
  u16* vT_i = (u16*)alloc((size_t)B*D*NI, 2);    // pre-transposed V, img stream
  u16* vT_c = (u16*)alloc((size_t)B*D*NC, 2);    // pre-transposed V, clinic stream
  (void)ws_size; (void)in_sizes; (void)n_in; (void)out_size;

  auto T = [&](const float* in_, u16* out_, int R, int C){
    transpose_kernel<<<dim3(C/64, R/64), dim3(64, 4), 0, stream>>>(in_, out_, R, C);
  };
  auto TV = [&](const u16* in_, u16* out_, int N, int LD, int coff){
    transpose_v_kernel<<<dim3(D/64, N/64, B), dim3(64, 4), 0, stream>>>(in_, out_, N, LD, coff);
  };
  auto G0 = [&](const u16* A, const u16* Bt, u16* out_, int M, int N, int K){
    gemm_bt<0><<<dim3(N/128, M/128), 256, 0, stream>>>(A, Bt, nullptr, out_, nullptr, M, N, K);
  };
  auto G1 = [&](const u16* A, const u16* Bt, const float* bias, u16* out_, int M, int N, int K){
    gemm_bt<1><<<dim3(N/128, M/128), 256, 0, stream>>>(A, Bt, bias, out_, nullptr, M, N, K);
  };
  auto G2 = [&](const u16* A, const u16* Bt, const float* bias, float* resid, int M, int N, int K){
    gemm_bt<2><<<dim3(N/128, M/128), 256, 0, stream>>>(A, Bt, bias, nullptr, resid, M, N, K);
  };
  auto ATT = [&](const u16* Q, const u16* K_, const u16* vTp, u16* O,
                 int Nq, int Nkv, int LDq, int LDk, float w_, int acc_){
    attn_zero_kernel<<<dim3(Nq/64, H, B), 256, 0, stream>>>(Q, K_, vTp, O, Nq, Nkv, LDq, LDk, w_, acc_);
  };
  auto CP = [&](const float* in_, float* out_, long n){
    copy_f32<<<1024, 256, 0, stream>>>(in_, out_, n / 4);
  };

  // ---- weight pre-transposes (K x N fp32 -> N x K bf16) ----
  for (int li = 0; li < L; li++){
    T(w_qkv + (size_t)li*D*3*D, wqkvT[li], D, 3*D);
    T(w_o   + (size_t)li*D*D,   woT[li],   D, D);
    T(w_ff1 + (size_t)li*D*FF,  ff1T[li],  D, FF);
    T(w_ff2 + (size_t)li*FF*D,  ff2T[li],  FF, D);
  }
  T(w_iq, wiqT, D, D); T(w_ik, wikT, D, D); T(w_iv, wivT, D, D);
  T(w_cq, wcqT, D, D); T(w_ck, wckT, D, D); T(w_cv, wcvT, D, D);
  T(w_io, wioT, D, D); T(w_co, wcoT, D, D);
  T(iff_w1, iff1T, D, FF); T(iff_w2, iff2T, FF, D);
  T(cff_w1, cff1T, D, FF); T(cff_w2, cff2T, FF, D);

  // ---- fp32 residual streams ----
  CP(img,    img_f, (long)RI*D);
  CP(clinic, cli_f, (long)RC*D);

  // ---- transformer stack ----
  for (int li = 0; li < L; li++){
    ln_kernel<<<RI, 256, 0, stream>>>(img_f, ln1_g + li*D, ln1_b + li*D, xn_i);
    G0(xn_i, wqkvT[li], qkvb, RI, 3*D, D);
    TV(qkvb, vT_i, NI, 3*D, 2*D);                      // V slice -> [b][768][NI]
    ATT(qkvb, qkvb + D, vT_i, ao_i, NI, NI, 3*D, 3*D, 1.0f, 0);
    G2(ao_i, woT[li], b_o + li*D, img_f, RI, D, D);
    ln_kernel<<<RI, 256, 0, stream>>>(img_f, ln2_g + li*D, ln2_b + li*D, xn_i);
    G1(xn_i, ff1T[li], b_ff1 + li*FF, h1, RI, FF, D);
    G2(h1, ff2T[li], b_ff2 + li*D, img_f, RI, D, FF);
  }

  // ---- cross block ----
  ln_kernel<<<RI, 256, 0, stream>>>(img_f, cn_i_g, cn_i_b, xn_i);
  ln_kernel<<<RC, 256, 0, stream>>>(cli_f, cn_c_g, cn_c_b, xn_c);
  u16* iq = qkvb;  u16* ik = qkvb + (size_t)RI*D;  u16* iv = qkvb + (size_t)2*RI*D;
  u16* cq = cqkv;  u16* ck = cqkv + (size_t)RC*D;  u16* cv = cqkv + (size_t)2*RC*D;
  G0(xn_i, wiqT, iq, RI, D, D);
  G0(xn_i, wikT, ik, RI, D, D);
  G0(xn_i, wivT, iv, RI, D, D);
  G0(xn_c, wcqT, cq, RC, D, D);
  G0(xn_c, wckT, ck, RC, D, D);
  G0(xn_c, wcvT, cv, RC, D, D);
  TV(iv, vT_i, NI, D, 0);
  TV(cv, vT_c, NC, D, 0);

  ATT(iq, ck, vT_c, ao_i, NI, NC, D, D, 0.5f, 0);
  ATT(iq, ik, vT_i, ao_i, NI, NI, D, D, 0.5f, 1);
  ATT(cq, ik, vT_i, ao_c, NC, NI, D, D, 0.5f, 0);
  ATT(cq, ck, vT_c, ao_c, NC, NC, D, D, 0.5f, 1);

  G2(ao_i, wioT, b_io, img_f, RI, D, D);
  G2(ao_c, wcoT, b_co, cli_f, RC, D, D);

  ln_kernel<<<RI, 256, 0, stream>>>(img_f, fn_i_g, fn_i_b, xn_i);
  G1(xn_i, iff1T, iff_b1, h1, RI, FF, D);
  G2(h1, iff2T, iff_b2, img_f, RI, D, FF);

  ln_kernel<<<RC, 256, 0, stream>>>(cli_f, fn_c_g, fn_c_b, xn_c);
  G1(xn_c, cff1T, cff_b1, h1, RC, FF, D);
  G2(h1, cff2T, cff_b2, cli_f, RC, D, FF);

  // ---- emit fp32 outputs (img then clinic, flat) ----
  CP(img_f, (float*)d_out,                (long)RI*D);
  CP(cli_f, (float*)d_out + (size_t)RI*D, (long)RC*D);
}

// Round 8
// 1105.801 us; speedup vs baseline: 1.3015x; 1.2514x over previous
//
#include <hip/hip_runtime.h>
#include <stdint.h>
#include <math.h>

typedef unsigned short u16;
typedef short  s16x8 __attribute__((ext_vector_type(8)));
typedef float  f32x4 __attribute__((ext_vector_type(4)));

#define DEVI __device__ __forceinline__

DEVI float b2f(u16 u){ union{unsigned int i; float f;} v; v.i = ((unsigned int)u)<<16; return v.f; }
DEVI u16 f2b(float f){
  union{float f; unsigned int i;} v; v.f = f;
  unsigned int r = v.i + 0x7FFFu + ((v.i >> 16) & 1u);   // RNE
  return (u16)(r >> 16);
}

// ---------------------------------------------------------------------------
// GEMM: C[M,N] = A[M,K] @ Bt[N,K]^T   (A,Bt bf16, fp32 accum, fp32 bias)
// MODE 0: store bf16 | MODE 1: bias + exact GELU, store bf16
// MODE 2: resid_f32[M,N] += acc + bias  (SPLITK>1: atomicAdd, bias on z==0)
// 128x128 tile, BK=32, 4 waves (2x2), 16x16x32 bf16 MFMA.
// K-loop: 2-deep register prefetch (loads for tile t+2 issued before compute
// of tile t) — hides global latency that serialized the round-7 version.
// niter = K/SPLITK/32 must be EVEN (all call shapes satisfy this).
// ---------------------------------------------------------------------------
template<int MODE, int SPLITK>
__launch_bounds__(256, 2)
__global__ void gemm_bt(const u16* __restrict__ A, const u16* __restrict__ Bt,
                        const float* __restrict__ bias, u16* __restrict__ outb,
                        float* __restrict__ resid, int M, int N, int K)
{
  __shared__ __align__(16) u16 lds_a[128*32];
  __shared__ __align__(16) u16 lds_b[128*32];
  const int tid = threadIdx.x;
  const int w = tid >> 6, l = tid & 63;
  const int q = l >> 4, r = l & 15;
  const int wm = w & 1, wn = w >> 1;
  const size_t m0 = (size_t)blockIdx.y * 128, n0 = (size_t)blockIdx.x * 128;
  const int kslice = K / SPLITK;
  const int kbeg = (SPLITK > 1) ? (int)blockIdx.z * kslice : 0;

  const int srow = tid >> 2;            // staging row 0..63
  const int scol = (tid & 3) * 8;       // staging col (u16) 0/8/16/24
  const u16* pa0 = A  + (m0 + srow)      * (size_t)K + kbeg + scol;
  const u16* pa1 = A  + (m0 + 64 + srow) * (size_t)K + kbeg + scol;
  const u16* pb0 = Bt + (n0 + srow)      * (size_t)K + kbeg + scol;
  const u16* pb1 = Bt + (n0 + 64 + srow) * (size_t)K + kbeg + scol;

  f32x4 acc[4][4];
  f32x4 zero = {0.f, 0.f, 0.f, 0.f};
#pragma unroll
  for (int i = 0; i < 4; i++)
#pragma unroll
    for (int j = 0; j < 4; j++) acc[i][j] = zero;

  auto compute = [&]() {
    s16x8 af[4], bfr[4];
#pragma unroll
    for (int mm = 0; mm < 4; mm++)
      af[mm] = *(const s16x8*)&lds_a[(wm*64 + mm*16 + r)*32 + q*8];
#pragma unroll
    for (int nn = 0; nn < 4; nn++)
      bfr[nn] = *(const s16x8*)&lds_b[(wn*64 + nn*16 + r)*32 + q*8];
#pragma unroll
    for (int mm = 0; mm < 4; mm++)
#pragma unroll
      for (int nn = 0; nn < 4; nn++)
        acc[mm][nn] = __builtin_amdgcn_mfma_f32_16x16x32_bf16(af[mm], bfr[nn], acc[mm][nn], 0, 0, 0);
  };

  // two register buffers (tiles t and t+1), 2-deep prefetch pipeline
  s16x8 a0_0 = *(const s16x8*)(pa0);
  s16x8 a1_0 = *(const s16x8*)(pa1);
  s16x8 b0_0 = *(const s16x8*)(pb0);
  s16x8 b1_0 = *(const s16x8*)(pb1);
  s16x8 a0_1 = *(const s16x8*)(pa0 + 32);
  s16x8 a1_1 = *(const s16x8*)(pa1 + 32);
  s16x8 b0_1 = *(const s16x8*)(pb0 + 32);
  s16x8 b1_1 = *(const s16x8*)(pb1 + 32);

  const int niter = kslice / 32;         // even by construction
  for (int it = 0; it < niter; it += 2){
    // ---- even tile (buffer 0) ----
    __syncthreads();                      // prior compute's LDS reads done
    *(s16x8*)&lds_a[srow*32 + scol]        = a0_0;
    *(s16x8*)&lds_a[(64 + srow)*32 + scol] = a1_0;
    *(s16x8*)&lds_b[srow*32 + scol]        = b0_0;
    *(s16x8*)&lds_b[(64 + srow)*32 + scol] = b1_0;
    __syncthreads();                      // tile visible
    if (it + 2 < niter){                  // issue loads for tile it+2 (no wait)
      int k2 = (it + 2) * 32;
      a0_0 = *(const s16x8*)(pa0 + k2);
      a1_0 = *(const s16x8*)(pa1 + k2);
      b0_0 = *(const s16x8*)(pb0 + k2);
      b1_0 = *(const s16x8*)(pb1 + k2);
    }
    compute();
    // ---- odd tile (buffer 1) ----
    __syncthreads();
    *(s16x8*)&lds_a[srow*32 + scol]        = a0_1;
    *(s16x8*)&lds_a[(64 + srow)*32 + scol] = a1_1;
    *(s16x8*)&lds_b[srow*32 + scol]        = b0_1;
    *(s16x8*)&lds_b[(64 + srow)*32 + scol] = b1_1;
    __syncthreads();
    if (it + 3 < niter){                  // issue loads for tile it+3
      int k3 = (it + 3) * 32;
      a0_1 = *(const s16x8*)(pa0 + k3);
      a1_1 = *(const s16x8*)(pa1 + k3);
      b0_1 = *(const s16x8*)(pb0 + k3);
      b1_1 = *(const s16x8*)(pb1 + k3);
    }
    compute();
  }

  // C/D layout: row = q*4+j, col = r  [m89/m91]
#pragma unroll
  for (int nn = 0; nn < 4; nn++){
    size_t col = n0 + wn*64 + nn*16 + r;
    float bv = 0.0f;
    if (MODE != 0 && (SPLITK == 1 || blockIdx.z == 0)) bv = bias[col];
#pragma unroll
    for (int mm = 0; mm < 4; mm++){
#pragma unroll
      for (int j = 0; j < 4; j++){
        size_t row = m0 + wm*64 + mm*16 + q*4 + j;
        float v = acc[mm][nn][j] + bv;
        if (MODE == 1) v = 0.5f * v * (1.0f + erff(v * 0.70710678118654752f));
        if (MODE == 2){
          if (SPLITK > 1) atomicAdd(&resid[row * N + col], v);
          else            resid[row * N + col] += v;
        } else {
          outb[row * N + col] = f2b(v);
        }
      }
    }
  }
}

// ---------------------------------------------------------------------------
// Zero-sink attention (flash-style). grid=(Nq/64, H, B), block=256 (4 waves).
// V comes PRE-TRANSPOSED in global: vT[b][768][Nkv] (head h at rows h*64..).
// K tile [32][64] LDS with xor-chunk swizzle applied on the GLOBAL side; Vt
// tile [64][32] linear. Both staged with contiguous b128 writes (conflict-
// free). Sink == online-softmax init m=0, l=1. Output at col h*64, LD=768.
// ---------------------------------------------------------------------------
__launch_bounds__(256, 2)
__global__ void attn_zero_kernel(const u16* __restrict__ Qp, const u16* __restrict__ Kp,
                                 const u16* __restrict__ vT, u16* __restrict__ Op,
                                 int Nq, int Nkv, int LDq, int LDk,
                                 float outw, int accumulate)
{
  __shared__ __align__(16) u16 lds_k[32*64];     // [kv][d], slot-chunk s holds global chunk s^(kv&7)
  __shared__ __align__(16) u16 lds_v[64*32];     // [d][kv], linear
  __shared__ __align__(16) u16 lds_p[4][16*40];  // per-wave P, pitch 40

  const int tid = threadIdx.x;
  const int w = tid >> 6, l = tid & 63;
  const int q = l >> 4, r = l & 15;
  const int h = blockIdx.y, b = blockIdx.z;
  const int q0 = blockIdx.x * 64 + w * 16;

  s16x8 qf[2];
  {
    const u16* qrow = Qp + (size_t)(b*Nq + q0 + r) * LDq + h*64;
    qf[0] = *(const s16x8*)(qrow + q*8);
    qf[1] = *(const s16x8*)(qrow + 32 + q*8);
  }

  float m_[4], l_[4];
  f32x4 o[4];
  f32x4 zero = {0.f, 0.f, 0.f, 0.f};
#pragma unroll
  for (int j = 0; j < 4; j++){ m_[j] = 0.0f; l_[j] = 1.0f; }   // zero-sink init
#pragma unroll
  for (int nn = 0; nn < 4; nn++) o[nn] = zero;

  // staging: K chunk c=tid -> kvrow=c>>3, slot-cc=c&7, global-cc=(c&7)^(kvrow&7)
  const u16* Kbase = Kp + (size_t)b * Nkv * LDk + h*64;
  const u16* gk = Kbase + (size_t)(tid >> 3) * LDk + (((tid & 7) ^ ((tid >> 3) & 7)) << 3);
  // Vt chunk c=tid -> drow=c>>2, cc=c&3 (linear)
  const u16* Vbase = vT + ((size_t)b * 768 + h*64) * (size_t)Nkv;
  const u16* gv = Vbase + (size_t)(tid >> 2) * Nkv + ((tid & 3) << 3);

  for (int kv0 = 0; kv0 < Nkv; kv0 += 32){
    s16x8 kvv = *(const s16x8*)(gk + (size_t)kv0 * LDk);
    s16x8 vvv = *(const s16x8*)(gv + kv0);
    __syncthreads();
    *(s16x8*)&lds_k[tid * 8] = kvv;       // contiguous b128 stores: conflict-free
    *(s16x8*)&lds_v[tid * 8] = vvv;
    __syncthreads();

    // S = (Q K^T) * 0.125 ; kv columns kk*16+r
    f32x4 s[2];
#pragma unroll
    for (int kk = 0; kk < 2; kk++){
      int row = kk*16 + r;
      s16x8 kf0 = *(const s16x8*)&lds_k[row*64 + ((q       ^ (row & 7)) << 3)];
      s16x8 kf1 = *(const s16x8*)&lds_k[row*64 + (((4 + q) ^ (row & 7)) << 3)];
      f32x4 t = zero;
      t = __builtin_amdgcn_mfma_f32_16x16x32_bf16(qf[0], kf0, t, 0, 0, 0);
      t = __builtin_amdgcn_mfma_f32_16x16x32_bf16(qf[1], kf1, t, 0, 0, 0);
      s[kk] = t * 0.125f;
    }

    // online softmax per q-row (row q*4+j owned by the 16 lanes of quad q)
    float p0[4], p1[4], al[4];
#pragma unroll
    for (int j = 0; j < 4; j++){
      float mx = fmaxf(s[0][j], s[1][j]);
#pragma unroll
      for (int d = 1; d < 16; d <<= 1) mx = fmaxf(mx, __shfl_xor(mx, d));
      float mn = fmaxf(m_[j], mx);
      float a  = __expf(m_[j] - mn);
      p0[j] = __expf(s[0][j] - mn);
      p1[j] = __expf(s[1][j] - mn);
      float rs = p0[j] + p1[j];
#pragma unroll
      for (int d = 1; d < 16; d <<= 1) rs += __shfl_xor(rs, d);
      l_[j] = l_[j] * a + rs;
      m_[j] = mn; al[j] = a;
    }
#pragma unroll
    for (int nn = 0; nn < 4; nn++){
      f32x4 t = o[nn];
#pragma unroll
      for (int j = 0; j < 4; j++) t[j] *= al[j];
      o[nn] = t;
    }

    // P: C-layout -> LDS -> A-layout (wave-private; pitch 40, aligned b128 reads)
    u16* P = &lds_p[w][0];
#pragma unroll
    for (int j = 0; j < 4; j++){
      P[(q*4 + j)*40 + r]      = f2b(p0[j]);
      P[(q*4 + j)*40 + 16 + r] = f2b(p1[j]);
    }
    s16x8 pf = *(const s16x8*)&P[r*40 + q*8];
#pragma unroll
    for (int nn = 0; nn < 4; nn++){
      int row = nn*16 + r;                   // d index (B-fragment n)
      s16x8 vf = *(const s16x8*)&lds_v[row*32 + (q << 3)];
      o[nn] = __builtin_amdgcn_mfma_f32_16x16x32_bf16(pf, vf, o[nn], 0, 0, 0);
    }
  }

#pragma unroll
  for (int j = 0; j < 4; j++){
    float inv = outw / l_[j];
    size_t rowoff = (size_t)(b*Nq + q0 + q*4 + j) * 768 + h*64;
#pragma unroll
    for (int nn = 0; nn < 4; nn++){
      float v = o[nn][j] * inv;
      size_t idx = rowoff + nn*16 + r;
      if (accumulate) v += b2f(Op[idx]);
      Op[idx] = f2b(v);
    }
  }
}

// ---------------------------------------------------------------------------
// LayerNorm over D=768 fp32 rows -> bf16 out. One block (256) per row.
// ---------------------------------------------------------------------------
__launch_bounds__(256)
__global__ void ln_kernel(const float* __restrict__ x, const float* __restrict__ g,
                          const float* __restrict__ bta, u16* __restrict__ out)
{
  __shared__ float red[8];
  const size_t row = blockIdx.x;
  const float* xr = x + row * 768;
  int t = threadIdx.x;
  float v0 = xr[t], v1 = xr[t + 256], v2 = xr[t + 512];
  float s  = v0 + v1 + v2;
  float s2 = v0*v0 + v1*v1 + v2*v2;
#pragma unroll
  for (int d = 1; d < 64; d <<= 1){ s += __shfl_xor(s, d); s2 += __shfl_xor(s2, d); }
  int w = t >> 6;
  if ((t & 63) == 0){ red[w] = s; red[4 + w] = s2; }
  __syncthreads();
  s  = red[0] + red[1] + red[2] + red[3];
  s2 = red[4] + red[5] + red[6] + red[7];
  float mean = s * (1.0f / 768.0f);
  float var  = s2 * (1.0f / 768.0f) - mean * mean;
  float rstd = rsqrtf(var + 1e-5f);
  u16* orow = out + row * 768;
  orow[t]       = f2b((v0 - mean) * rstd * g[t]       + bta[t]);
  orow[t + 256] = f2b((v1 - mean) * rstd * g[t + 256] + bta[t + 256]);
  orow[t + 512] = f2b((v2 - mean) * rstd * g[t + 512] + bta[t + 512]);
}

// fp32 -> bf16 transpose (R x C -> C x R), dims multiples of 64. block (64,4).
__global__ void transpose_kernel(const float* __restrict__ in, u16* __restrict__ out, int R, int C)
{
  __shared__ u16 tile[64][65];
  int c0 = blockIdx.x * 64, r0 = blockIdx.y * 64;
  for (int i = threadIdx.y; i < 64; i += 4)
    tile[i][threadIdx.x] = f2b(in[(size_t)(r0 + i) * C + c0 + threadIdx.x]);
  __syncthreads();
  for (int i = threadIdx.y; i < 64; i += 4)
    out[(size_t)(c0 + i) * R + r0 + threadIdx.x] = tile[threadIdx.x][i];
}

// batched u16 transpose for V: in = per-batch [N][LD] slab at col offset coff,
// out = [b][768][N]. grid (768/64, N/64, B), block (64,4).
__global__ void transpose_v_kernel(const u16* __restrict__ in, u16* __restrict__ out,
                                   int N, int LD, int coff)
{
  __shared__ u16 tile[64][65];
  int bz = blockIdx.z;
  int c0 = blockIdx.x * 64, n0 = blockIdx.y * 64;
  const u16* ib = in + ((size_t)bz * N + n0) * LD + coff + c0;
  for (int i = threadIdx.y; i < 64; i += 4)
    tile[i][threadIdx.x] = ib[(size_t)i * LD + threadIdx.x];     // token n0+i, chan c0+tx
  __syncthreads();
  u16* ob = out + ((size_t)bz * 768 + c0) * N + n0;
  for (int i = threadIdx.y; i < 64; i += 4)
    ob[(size_t)i * N + threadIdx.x] = tile[threadIdx.x][i];      // chan c0+i, token n0+tx
}

// fp32 vectorized copy (n multiple of 4).
__global__ void copy_f32(const float* __restrict__ in, float* __restrict__ out, long n4){
  long i = (long)blockIdx.x * blockDim.x + threadIdx.x;
  long stride = (long)gridDim.x * blockDim.x;
  const f32x4* in4 = (const f32x4*)in;
  f32x4* out4 = (f32x4*)out;
  for (; i < n4; i += stride) out4[i] = in4[i];
}

// ---------------------------------------------------------------------------
extern "C" void kernel_launch(void* const* d_in, const int* in_sizes, int n_in,
                              void* d_out, int out_size, void* d_ws, size_t ws_size,
                              hipStream_t stream)
{
  const int B = 4, NI = 1024, NC = 256, D = 768, FF = 3072, H = 12, L = 2;
  const int RI = B * NI;   // 4096 img rows
  const int RC = B * NC;   // 1024 clinic rows

  const float* img    = (const float*)d_in[0];
  const float* clinic = (const float*)d_in[1];
  const float* ln1_g  = (const float*)d_in[2];
  const float* ln1_b  = (const float*)d_in[3];
  const float* w_qkv  = (const float*)d_in[4];
  const float* w_o    = (const float*)d_in[5];
  const float* b_o    = (const float*)d_in[6];
  const float* ln2_g  = (const float*)d_in[7];
  const float* ln2_b  = (const float*)d_in[8];
  const float* w_ff1  = (const float*)d_in[9];
  const float* b_ff1  = (const float*)d_in[10];
  const float* w_ff2  = (const float*)d_in[11];
  const float* b_ff2  = (const float*)d_in[12];
  const float* cn_i_g = (const float*)d_in[13];
  const float* cn_i_b = (const float*)d_in[14];
  const float* cn_c_g = (const float*)d_in[15];
  const float* cn_c_b = (const float*)d_in[16];
  const float* w_iq   = (const float*)d_in[17];
  const float* w_ik   = (const float*)d_in[18];
  const float* w_iv   = (const float*)d_in[19];
  const float* w_cq   = (const float*)d_in[20];
  const float* w_ck   = (const float*)d_in[21];
  const float* w_cv   = (const float*)d_in[22];
  const float* w_io   = (const float*)d_in[23];
  const float* b_io   = (const float*)d_in[24];
  const float* w_co   = (const float*)d_in[25];
  const float* b_co   = (const float*)d_in[26];
  const float* fn_i_g = (const float*)d_in[27];
  const float* fn_i_b = (const float*)d_in[28];
  const float* fn_c_g = (const float*)d_in[29];
  const float* fn_c_b = (const float*)d_in[30];
  const float* iff_w1 = (const float*)d_in[31];
  const float* iff_b1 = (const float*)d_in[32];
  const float* iff_w2 = (const float*)d_in[33];
  const float* iff_b2 = (const float*)d_in[34];
  const float* cff_w1 = (const float*)d_in[35];
  const float* cff_b1 = (const float*)d_in[36];
  const float* cff_w2 = (const float*)d_in[37];
  const float* cff_b2 = (const float*)d_in[38];

  // ---- workspace carve (~121 MB) ----
  char* ws = (char*)d_ws;
  size_t off = 0;
  auto alloc = [&](size_t elems, size_t esz) -> void* {
    void* p = ws + off;
    off += ((elems * esz) + 255) & ~(size_t)255;
    return p;
  };
  u16* wqkvT[2]; u16* woT[2]; u16* ff1T[2]; u16* ff2T[2];
  for (int i = 0; i < 2; i++) wqkvT[i] = (u16*)alloc((size_t)3*D*D, 2);
  for (int i = 0; i < 2; i++) woT[i]   = (u16*)alloc((size_t)D*D, 2);
  for (int i = 0; i < 2; i++) ff1T[i]  = (u16*)alloc((size_t)FF*D, 2);
  for (int i = 0; i < 2; i++) ff2T[i]  = (u16*)alloc((size_t)D*FF, 2);
  u16* wiqkvT = (u16*)alloc((size_t)3*D*D, 2);   // fused [iq|ik|iv] as [2304][768]
  u16* wcqkvT = (u16*)alloc((size_t)3*D*D, 2);   // fused [cq|ck|cv]
  u16* wioT = (u16*)alloc((size_t)D*D, 2); u16* wcoT = (u16*)alloc((size_t)D*D, 2);
  u16* iff1T = (u16*)alloc((size_t)FF*D, 2); u16* iff2T = (u16*)alloc((size_t)D*FF, 2);
  u16* cff1T = (u16*)alloc((size_t)FF*D, 2); u16* cff2T = (u16*)alloc((size_t)D*FF, 2);

  float* img_f = (float*)alloc((size_t)RI*D, 4);   // fp32 residual streams
  float* cli_f = (float*)alloc((size_t)RC*D, 4);
  u16* xn_i = (u16*)alloc((size_t)RI*D, 2);
  u16* xn_c = (u16*)alloc((size_t)RC*D, 2);
  // shared region: {qkvb | cqkv} (projections) or {h1} (FFN hidden)
  u16* region = (u16*)alloc((size_t)RI*FF, 2);   // RI*FF > RI*3D + RC*3D
  u16* qkvb = region;
  u16* cqkv = region + (size_t)RI*3*D;
  u16* h1   = region;
  u16* ao_i = (u16*)alloc((size_t)RI*D, 2);      // attention outputs (bf16)
  u16* ao_c = (u16*)alloc((size_t)RC*D, 2);
  u16* vT_i = (u16*)alloc((size_t)B*D*NI, 2);    // pre-transposed V, img stream
  u16* vT_c = (u16*)alloc((size_t)B*D*NC, 2);    // pre-transposed V, clinic stream
  (void)ws_size; (void)in_sizes; (void)n_in; (void)out_size;

  auto T = [&](const float* in_, u16* out_, int R, int C){
    transpose_kernel<<<dim3(C/64, R/64), dim3(64, 4), 0, stream>>>(in_, out_, R, C);
  };
  auto TV = [&](const u16* in_, u16* out_, int N, int LD, int coff){
    transpose_v_kernel<<<dim3(D/64, N/64, B), dim3(64, 4), 0, stream>>>(in_, out_, N, LD, coff);
  };
  auto G0 = [&](const u16* A, const u16* Bt, u16* out_, int M, int N, int K){
    gemm_bt<0,1><<<dim3(N/128, M/128), 256, 0, stream>>>(A, Bt, nullptr, out_, nullptr, M, N, K);
  };
  auto G1 = [&](const u16* A, const u16* Bt, const float* bias, u16* out_, int M, int N, int K){
    gemm_bt<1,1><<<dim3(N/128, M/128), 256, 0, stream>>>(A, Bt, bias, out_, nullptr, M, N, K);
  };
  auto G2 = [&](const u16* A, const u16* Bt, const float* bias, float* resid, int M, int N, int K, int splitk){
    if (splitk == 4)
      gemm_bt<2,4><<<dim3(N/128, M/128, 4), 256, 0, stream>>>(A, Bt, bias, nullptr, resid, M, N, K);
    else if (splitk == 2)
      gemm_bt<2,2><<<dim3(N/128, M/128, 2), 256, 0, stream>>>(A, Bt, bias, nullptr, resid, M, N, K);
    else
      gemm_bt<2,1><<<dim3(N/128, M/128, 1), 256, 0, stream>>>(A, Bt, bias, nullptr, resid, M, N, K);
  };
  auto ATT = [&](const u16* Q, const u16* K_, const u16* vTp, u16* O,
                 int Nq, int Nkv, int LDq, int LDk, float w_, int acc_){
    attn_zero_kernel<<<dim3(Nq/64, H, B), 256, 0, stream>>>(Q, K_, vTp, O, Nq, Nkv, LDq, LDk, w_, acc_);
  };
  auto CP = [&](const float* in_, float* out_, long n){
    copy_f32<<<1024, 256, 0, stream>>>(in_, out_, n / 4);
  };

  // ---- weight pre-transposes (K x N fp32 -> N x K bf16) ----
  for (int li = 0; li < L; li++){
    T(w_qkv + (size_t)li*D*3*D, wqkvT[li], D, 3*D);
    T(w_o   + (size_t)li*D*D,   woT[li],   D, D);
    T(w_ff1 + (size_t)li*D*FF,  ff1T[li],  D, FF);
    T(w_ff2 + (size_t)li*FF*D,  ff2T[li],  FF, D);
  }
  T(w_iq, wiqkvT,              D, D);
  T(w_ik, wiqkvT + (size_t)D*D,   D, D);
  T(w_iv, wiqkvT + (size_t)2*D*D, D, D);
  T(w_cq, wcqkvT,              D, D);
  T(w_ck, wcqkvT + (size_t)D*D,   D, D);
  T(w_cv, wcqkvT + (size_t)2*D*D, D, D);
  T(w_io, wioT, D, D); T(w_co, wcoT, D, D);
  T(iff_w1, iff1T, D, FF); T(iff_w2, iff2T, FF, D);
  T(cff_w1, cff1T, D, FF); T(cff_w2, cff2T, FF, D);

  // ---- fp32 residual streams ----
  CP(img,    img_f, (long)RI*D);
  CP(clinic, cli_f, (long)RC*D);

  // ---- transformer stack ----
  for (int li = 0; li < L; li++){
    ln_kernel<<<RI, 256, 0, stream>>>(img_f, ln1_g + li*D, ln1_b + li*D, xn_i);
    G0(xn_i, wqkvT[li], qkvb, RI, 3*D, D);
    TV(qkvb, vT_i, NI, 3*D, 2*D);                      // V slice -> [b][768][NI]
    ATT(qkvb, qkvb + D, vT_i, ao_i, NI, NI, 3*D, 3*D, 1.0f, 0);
    G2(ao_i, woT[li], b_o + li*D, img_f, RI, D, D, 2);
    ln_kernel<<<RI, 256, 0, stream>>>(img_f, ln2_g + li*D, ln2_b + li*D, xn_i);
    G1(xn_i, ff1T[li], b_ff1 + li*FF, h1, RI, FF, D);
    G2(h1, ff2T[li], b_ff2 + li*D, img_f, RI, D, FF, 2);
  }

  // ---- cross block ----
  ln_kernel<<<RI, 256, 0, stream>>>(img_f, cn_i_g, cn_i_b, xn_i);
  ln_kernel<<<RC, 256, 0, stream>>>(cli_f, cn_c_g, cn_c_b, xn_c);
  u16* iqkv = qkvb;   // [RI][3D]: iq | ik | iv
  u16* cqk  = cqkv;   // [RC][3D]: cq | ck | cv
  G0(xn_i, wiqkvT, iqkv, RI, 3*D, D);
  G0(xn_c, wcqkvT, cqk,  RC, 3*D, D);
  TV(iqkv, vT_i, NI, 3*D, 2*D);
  TV(cqk,  vT_c, NC, 3*D, 2*D);

  ATT(iqkv, cqk + D,  vT_c, ao_i, NI, NC, 3*D, 3*D, 0.5f, 0);
  ATT(iqkv, iqkv + D, vT_i, ao_i, NI, NI, 3*D, 3*D, 0.5f, 1);
  ATT(cqk,  iqkv + D, vT_i, ao_c, NC, NI, 3*D, 3*D, 0.5f, 0);
  ATT(cqk,  cqk + D,  vT_c, ao_c, NC, NC, 3*D, 3*D, 0.5f, 1);

  G2(ao_i, wioT, b_io, img_f, RI, D, D, 2);
  G2(ao_c, wcoT, b_co, cli_f, RC, D, D, 4);

  ln_kernel<<<RI, 256, 0, stream>>>(img_f, fn_i_g, fn_i_b, xn_i);
  G1(xn_i, iff1T, iff_b1, h1, RI, FF, D);
  G2(h1, iff2T, iff_b2, img_f, RI, D, FF, 2);

  ln_kernel<<<RC, 256, 0, stream>>>(cli_f, fn_c_g, fn_c_b, xn_c);
  G1(xn_c, cff1T, cff_b1, h1, RC, FF, D);
  G2(h1, cff2T, cff_b2, cli_f, RC, D, FF, 4);

  // ---- emit fp32 outputs (img then clinic, flat) ----
  CP(img_f, (float*)d_out,                (long)RI*D);
  CP(cli_f, (float*)d_out + (size_t)RI*D, (long)RC*D);
}